// Round 4
// baseline (1258.490 us; speedup 1.0000x reference)
//
#include <hip/hip_runtime.h>
#include <stdint.h>

// Problem constants (pad_x = 0 since T % PATCH == 0)
#define B_    16
#define C_    128
#define T_    16384
#define W_    2048      // wordnum
#define CP_   1024      // MIDC * PATCH

typedef unsigned short u16;
typedef __attribute__((ext_vector_type(4))) unsigned short u16x4;
typedef __attribute__((ext_vector_type(8))) unsigned short u16x8;
typedef __attribute__((ext_vector_type(8))) short bf16x8;   // MFMA A/B frag (8 bf16)
typedef __attribute__((ext_vector_type(4))) float f32x4;    // MFMA C/D frag

// Workspace layout (bytes) — attnT ALIASES kT (kT dead after GEMM1):
//  q     bf16 [16][2048][1024]     67108864   @ 0
//  kT    bf16 [16][1024][2048]     67108864   @ 67108864
//  attnT bf16 [16][16386][128]     67117056   @ 67108864   (alias; pad rows zeroed AFTER gemm1)
//  vT    bf16 [16][1024][2048]     67108864   @ 134234112
//  kvT   bf16 [16][1024][1024]     33554432   @ 201342976
//  w2    bf16 [3][128][128]           98304   @ 234897408
//  total                                        234995712  (~224 MB)
#define OFF_Q     0ull
#define OFF_KT    67108864ull
#define OFF_ATT   67108864ull
#define OFF_VT    134234112ull
#define OFF_KVT   201342976ull
#define OFF_W2    234897408ull
#define WS_NEEDED 234995712ull

__device__ __forceinline__ u16 f2bf(float f) {
  union { float f; uint32_t u; } v; v.f = f;
  return (u16)((v.u + 0x7FFFu + ((v.u >> 16) & 1u)) >> 16);  // RNE, no NaN inputs here
}
__device__ __forceinline__ float bf2f(u16 h) {
  union { uint32_t u; float f; } v; v.u = ((uint32_t)h) << 16;
  return v.f;
}
__device__ __forceinline__ void gload16(const void* g, void* l) {
  __builtin_amdgcn_global_load_lds(
      (const __attribute__((address_space(1))) uint32_t*)g,
      (__attribute__((address_space(3))) uint32_t*)l, 16, 0, 0);
}
__device__ __forceinline__ float wred_max(float v) {
  #pragma unroll
  for (int o = 32; o; o >>= 1) v = fmaxf(v, __shfl_xor(v, o));
  return v;
}
__device__ __forceinline__ float wred_sum(float v) {
  #pragma unroll
  for (int o = 32; o; o >>= 1) v += __shfl_xor(v, o);
  return v;
}

// ---------------------------------------------------------------------------
// conv_q: grouped conv2d (5 over wordnum, pointwise over patch) on condition.
// Writes q_raw bf16 in attention layout: q[b][w][m*8+p], row stride 1024.
// ---------------------------------------------------------------------------
__global__ __launch_bounds__(256) void conv_q_kernel(
    const float* __restrict__ cond, const float* __restrict__ wQ,
    const float* __restrict__ bQ, u16* __restrict__ qout)
{
  __shared__ __align__(16) float sIn[128 * 96];   // [ch][ww*8+p], ww 0..11 (2-word halo each side)
  const int b = blockIdx.y, w0 = blockIdx.x * 8;
  const float* cb = cond + (size_t)b * C_ * T_;
  const int tlo = w0 * 8 - 16;
  for (int f = threadIdx.x; f < 3072; f += 256) {
    int ch = f / 24;
    int off = (f % 24) * 4;
    int t = tlo + off;
    float4 val;
    if (t >= 0 && t <= T_ - 4) {
      val = *(const float4*)(cb + (size_t)ch * T_ + t);
    } else {
      float tmp[4];
      #pragma unroll
      for (int e = 0; e < 4; e++) { int tt = t + e; tmp[e] = (tt >= 0 && tt < T_) ? cb[(size_t)ch * T_ + tt] : 0.f; }
      val = make_float4(tmp[0], tmp[1], tmp[2], tmp[3]);
    }
    *(float4*)&sIn[ch * 96 + off] = val;
  }
  __syncthreads();

  const int m = threadIdx.x & 127, p0 = (threadIdx.x >> 7) * 4;
  const int g = m >> 5;                      // 128 out-ch / 4 groups
  float acc[8][4];
  #pragma unroll
  for (int w = 0; w < 8; w++) { acc[w][0] = acc[w][1] = acc[w][2] = acc[w][3] = 0.f; }
  const float* wm = wQ + (size_t)m * 160;    // wQ[m][ic][dt], 32*5
  const float* sg = sIn + g * 32 * 96 + p0;
  for (int ic = 0; ic < 32; ic++) {
    float w5[5];
    #pragma unroll
    for (int d = 0; d < 5; d++) w5[d] = wm[ic * 5 + d];
    const float* srow = sg + ic * 96;
    float4 vv[12];
    #pragma unroll
    for (int ww = 0; ww < 12; ww++) vv[ww] = *(const float4*)(srow + ww * 8);
    #pragma unroll
    for (int d = 0; d < 5; d++) {
      #pragma unroll
      for (int w = 0; w < 8; w++) {
        float4 x = vv[w + d];
        acc[w][0] += w5[d] * x.x; acc[w][1] += w5[d] * x.y;
        acc[w][2] += w5[d] * x.z; acc[w][3] += w5[d] * x.w;
      }
    }
  }
  const float bias = bQ[m];
  #pragma unroll
  for (int w = 0; w < 8; w++) {
    u16x4 o;
    #pragma unroll
    for (int e = 0; e < 4; e++) o[e] = f2bf(acc[w][e] + bias);
    *(u16x4*)(qout + ((size_t)(b * W_ + w0 + w) * CP_ + m * 8 + p0)) = o;
  }
}

// ---------------------------------------------------------------------------
// conv_kv: grouped conv2d over x -> 256 ch (k: 0..127 [+mask], v: 128..255).
// Writes TRANSPOSED bf16: kT[b][i=oc*8+p][w], vT[b][j][w]  (row stride 2048).
// ---------------------------------------------------------------------------
__global__ __launch_bounds__(512) void conv_kv_kernel(
    const float* __restrict__ x, const float* __restrict__ wKV,
    const float* __restrict__ bKV, const float* __restrict__ mask,
    u16* __restrict__ kT, u16* __restrict__ vT)
{
  __shared__ __align__(16) float sIn[128 * 96];
  const int b = blockIdx.y, w0 = blockIdx.x * 8;
  const float* xb = x + (size_t)b * C_ * T_;
  const int tlo = w0 * 8 - 16;
  for (int f = threadIdx.x; f < 3072; f += 512) {
    int ch = f / 24;
    int off = (f % 24) * 4;
    int t = tlo + off;
    float4 val;
    if (t >= 0 && t <= T_ - 4) {
      val = *(const float4*)(xb + (size_t)ch * T_ + t);
    } else {
      float tmp[4];
      #pragma unroll
      for (int e = 0; e < 4; e++) { int tt = t + e; tmp[e] = (tt >= 0 && tt < T_) ? xb[(size_t)ch * T_ + tt] : 0.f; }
      val = make_float4(tmp[0], tmp[1], tmp[2], tmp[3]);
    }
    *(float4*)&sIn[ch * 96 + off] = val;
  }
  __syncthreads();

  const int oc = threadIdx.x >> 1, p0 = (threadIdx.x & 1) * 4;
  const int g = oc >> 6;                     // 256 out-ch / 4 groups
  float acc[8][4];
  #pragma unroll
  for (int w = 0; w < 8; w++) { acc[w][0] = acc[w][1] = acc[w][2] = acc[w][3] = 0.f; }
  const float* wm = wKV + (size_t)oc * 160;
  const float* sg = sIn + g * 32 * 96 + p0;
  for (int ic = 0; ic < 32; ic++) {
    float w5[5];
    #pragma unroll
    for (int d = 0; d < 5; d++) w5[d] = wm[ic * 5 + d];
    const float* srow = sg + ic * 96;
    float4 vv[12];
    #pragma unroll
    for (int ww = 0; ww < 12; ww++) vv[ww] = *(const float4*)(srow + ww * 8);
    #pragma unroll
    for (int d = 0; d < 5; d++) {
      #pragma unroll
      for (int w = 0; w < 8; w++) {
        float4 xv = vv[w + d];
        acc[w][0] += w5[d] * xv.x; acc[w][1] += w5[d] * xv.y;
        acc[w][2] += w5[d] * xv.z; acc[w][3] += w5[d] * xv.w;
      }
    }
  }
  const float bias = bKV[oc];
  if (oc < 128) {
    const float* mb = mask + (((size_t)(b * 128 + oc)) * W_ + w0) * 8 + p0;
    float mv[8][4];
    #pragma unroll
    for (int w = 0; w < 8; w++) {
      float4 t4 = *(const float4*)(mb + w * 8);
      mv[w][0] = t4.x; mv[w][1] = t4.y; mv[w][2] = t4.z; mv[w][3] = t4.w;
    }
    #pragma unroll
    for (int pp = 0; pp < 4; pp++) {
      u16x8 o;
      #pragma unroll
      for (int w = 0; w < 8; w++) o[w] = f2bf(acc[w][pp] + bias + mv[w][pp]);
      *(u16x8*)(kT + ((size_t)(b * CP_ + oc * 8 + p0 + pp)) * W_ + w0) = o;
    }
  } else {
    const int j = (oc - 128) * 8;
    #pragma unroll
    for (int pp = 0; pp < 4; pp++) {
      u16x8 o;
      #pragma unroll
      for (int w = 0; w < 8; w++) o[w] = f2bf(acc[w][pp] + bias);
      *(u16x8*)(vT + ((size_t)(b * CP_ + j + p0 + pp)) * W_ + w0) = o;
    }
  }
}

// ---------------------------------------------------------------------------
// softmax over contiguous rows, in place.
// ---------------------------------------------------------------------------
__global__ __launch_bounds__(256) void softmax_q_kernel(u16* __restrict__ q)
{
  __shared__ float red[4];
  u16* p = q + (size_t)blockIdx.x * CP_ + threadIdx.x * 4;
  u16x4 raw = *(const u16x4*)p;
  float xv[4];
  #pragma unroll
  for (int e = 0; e < 4; e++) xv[e] = bf2f(raw[e]);
  float mx = fmaxf(fmaxf(xv[0], xv[1]), fmaxf(xv[2], xv[3]));
  mx = wred_max(mx);
  if ((threadIdx.x & 63) == 0) red[threadIdx.x >> 6] = mx;
  __syncthreads();
  mx = fmaxf(fmaxf(red[0], red[1]), fmaxf(red[2], red[3]));
  __syncthreads();
  float ev[4], s = 0.f;
  #pragma unroll
  for (int e = 0; e < 4; e++) { ev[e] = __expf(xv[e] - mx); s += ev[e]; }
  s = wred_sum(s);
  if ((threadIdx.x & 63) == 0) red[threadIdx.x >> 6] = s;
  __syncthreads();
  s = red[0] + red[1] + red[2] + red[3];
  float inv = 1.f / s;
  u16x4 o;
  #pragma unroll
  for (int e = 0; e < 4; e++) o[e] = f2bf(ev[e] * inv);
  *(u16x4*)p = o;
}

__global__ __launch_bounds__(256) void softmax_k_kernel(u16* __restrict__ kT)
{
  __shared__ float red[4];
  u16* p = kT + (size_t)blockIdx.x * W_ + threadIdx.x * 8;
  u16x8 raw = *(const u16x8*)p;
  float xv[8];
  #pragma unroll
  for (int e = 0; e < 8; e++) xv[e] = bf2f(raw[e]);
  float mx = -3.4e38f;
  #pragma unroll
  for (int e = 0; e < 8; e++) mx = fmaxf(mx, xv[e]);
  mx = wred_max(mx);
  if ((threadIdx.x & 63) == 0) red[threadIdx.x >> 6] = mx;
  __syncthreads();
  mx = fmaxf(fmaxf(red[0], red[1]), fmaxf(red[2], red[3]));
  __syncthreads();
  float ev[8], s = 0.f;
  #pragma unroll
  for (int e = 0; e < 8; e++) { ev[e] = __expf(xv[e] - mx); s += ev[e]; }
  s = wred_sum(s);
  if ((threadIdx.x & 63) == 0) red[threadIdx.x >> 6] = s;
  __syncthreads();
  s = red[0] + red[1] + red[2] + red[3];
  float inv = 1.f / s;
  u16x8 o;
  #pragma unroll
  for (int e = 0; e < 8; e++) o[e] = f2bf(ev[e] * inv);
  *(u16x8*)p = o;
}

// ---------------------------------------------------------------------------
// prep: pack w2[dt][c][m] = wOut[c][m][dt] (bf16). (No attnT writes here —
// attnT aliases kT, which is still live until gemm1 completes.)
// ---------------------------------------------------------------------------
__global__ __launch_bounds__(256) void prep_kernel(
    const float* __restrict__ wOut, u16* __restrict__ w2)
{
  int idx = blockIdx.x * 256 + threadIdx.x;
  if (idx < 3 * 128 * 128) {
    int dt = idx >> 14, c = (idx >> 7) & 127, m = idx & 127;
    w2[idx] = f2bf(wOut[((size_t)c * 128 + m) * 3 + dt]);
  }
}

// zero the attnT pad rows (row 0 and row T_+1 per batch). Launched AFTER gemm1.
__global__ __launch_bounds__(256) void zero_pad_kernel(u16* __restrict__ attnT)
{
  int idx = blockIdx.x * 256 + threadIdx.x;   // 16*2*128 = 4096
  int b = idx >> 8, r = (idx >> 7) & 1, m = idx & 127;
  attnT[((size_t)b * (T_ + 2) + (r ? (T_ + 1) : 0)) * 128 + m] = 0;
}

// ---------------------------------------------------------------------------
// gemm_bt: C[M x N] = A[M x K] * Bt[N x K]^T  (bf16 in, f32 acc), batched over z.
// 128x128 tile, BK=32, 4 waves (2x2), mfma_f32_16x16x32_bf16.
// XOR k-slot swizzle (slot ^= (row>>1)&3) on BOTH global source (staging) and
// LDS read; LDS dest stays linear (global_load_lds requirement, rule #21).
// MODE 0: out[b][row][col]  (kvT)
// MODE 1: out = attnT[b][1 + row*8 + (col&7)][col>>3]  (padded transposed attn)
// ---------------------------------------------------------------------------
template<int MODE>
__global__ __launch_bounds__(256) void gemm_bt_kernel(
    const u16* __restrict__ A, const u16* __restrict__ Bt, u16* __restrict__ out,
    int M, int N, int K)
{
  __shared__ __align__(16) u16 ldsA[4096];
  __shared__ __align__(16) u16 ldsB[4096];
  const int b = blockIdx.z;
  const int i0 = blockIdx.x * 128, j0 = blockIdx.y * 128;
  const int tid = threadIdx.x, lane = tid & 63, wv = tid >> 6;
  const int wr = wv >> 1, wc = wv & 1;
  const u16* Ab = A + (size_t)b * M * K + (size_t)i0 * K;
  const u16* Bb = Bt + (size_t)b * N * K + (size_t)j0 * K;

  const int srow0 = wv * 32 + (lane >> 2);
  const int sslot = lane & 3;
  const int frow = lane & 15, fkq = lane >> 4;

  f32x4 acc[4][4];
  #pragma unroll
  for (int m = 0; m < 4; m++)
    #pragma unroll
    for (int n = 0; n < 4; n++) acc[m][n] = (f32x4)0.f;

  for (int kt = 0; kt < K; kt += 32) {
    #pragma unroll
    for (int q = 0; q < 2; q++) {
      int row = srow0 + q * 16;
      int gslot = sslot ^ ((row >> 1) & 3);
      gload16(Ab + (size_t)row * K + kt + gslot * 8, &ldsA[row * 32 + sslot * 8]);
      gload16(Bb + (size_t)row * K + kt + gslot * 8, &ldsB[row * 32 + sslot * 8]);
    }
    __syncthreads();
    bf16x8 af[4], bf[4];
    #pragma unroll
    for (int m = 0; m < 4; m++) {
      int row = wr * 64 + m * 16 + frow;
      af[m] = *(const bf16x8*)&ldsA[row * 32 + (fkq ^ ((row >> 1) & 3)) * 8];
    }
    #pragma unroll
    for (int n = 0; n < 4; n++) {
      int row = wc * 64 + n * 16 + frow;
      bf[n] = *(const bf16x8*)&ldsB[row * 32 + (fkq ^ ((row >> 1) & 3)) * 8];
    }
    #pragma unroll
    for (int m = 0; m < 4; m++)
      #pragma unroll
      for (int n = 0; n < 4; n++)
        acc[m][n] = __builtin_amdgcn_mfma_f32_16x16x32_bf16(af[m], bf[n], acc[m][n], 0, 0, 0);
    __syncthreads();
  }

  const int rb = (lane >> 4) * 4, cl = lane & 15;
  #pragma unroll
  for (int m = 0; m < 4; m++) {
    #pragma unroll
    for (int n = 0; n < 4; n++) {
      #pragma unroll
      for (int r = 0; r < 4; r++) {
        int gr = i0 + wr * 64 + m * 16 + rb + r;
        int gc = j0 + wc * 64 + n * 16 + cl;
        u16 v = f2bf(acc[m][n][r]);
        if (MODE == 0) {
          out[((size_t)b * M + gr) * N + gc] = v;
        } else {
          out[((size_t)b * (T_ + 2) + 1 + (size_t)gr * 8 + (gc & 7)) * 128 + (gc >> 3)] = v;
        }
      }
    }
  }
}

// ---------------------------------------------------------------------------
// convout: final conv1d as 3 shifted GEMMs accumulated in one K-loop.
// C[c][t] = bOut[c] + sum_dt sum_m w2[dt][c][m] * attnT[b][t+dt][m]
// ---------------------------------------------------------------------------
__global__ __launch_bounds__(256) void convout_kernel(
    const u16* __restrict__ w2, const u16* __restrict__ attnT,
    const float* __restrict__ bOut, float* __restrict__ out)
{
  __shared__ __align__(16) u16 ldsA[4096];
  __shared__ __align__(16) u16 ldsB[4096];
  const int b = blockIdx.z;
  const int t0 = blockIdx.y * 128;
  const int tid = threadIdx.x, lane = tid & 63, wv = tid >> 6;
  const int wr = wv >> 1, wc = wv & 1;
  const u16* Bb = attnT + (size_t)b * (T_ + 2) * 128;

  const int srow0 = wv * 32 + (lane >> 2);
  const int sslot = lane & 3;
  const int frow = lane & 15, fkq = lane >> 4;

  f32x4 acc[4][4];
  #pragma unroll
  for (int m = 0; m < 4; m++)
    #pragma unroll
    for (int n = 0; n < 4; n++) acc[m][n] = (f32x4)0.f;

  for (int s = 0; s < 12; s++) {
    int dt = s >> 2, kk = (s & 3) * 32;
    #pragma unroll
    for (int q = 0; q < 2; q++) {
      int row = srow0 + q * 16;
      int gslot = sslot ^ ((row >> 1) & 3);
      gload16(w2 + (size_t)dt * 16384 + (size_t)row * 128 + kk + gslot * 8,
              &ldsA[row * 32 + sslot * 8]);
      gload16(Bb + (size_t)(t0 + row + dt) * 128 + kk + gslot * 8,
              &ldsB[row * 32 + sslot * 8]);
    }
    __syncthreads();
    bf16x8 af[4], bf[4];
    #pragma unroll
    for (int m = 0; m < 4; m++) {
      int row = wr * 64 + m * 16 + frow;
      af[m] = *(const bf16x8*)&ldsA[row * 32 + (fkq ^ ((row >> 1) & 3)) * 8];
    }
    #pragma unroll
    for (int n = 0; n < 4; n++) {
      int row = wc * 64 + n * 16 + frow;
      bf[n] = *(const bf16x8*)&ldsB[row * 32 + (fkq ^ ((row >> 1) & 3)) * 8];
    }
    #pragma unroll
    for (int m = 0; m < 4; m++)
      #pragma unroll
      for (int n = 0; n < 4; n++)
        acc[m][n] = __builtin_amdgcn_mfma_f32_16x16x32_bf16(af[m], bf[n], acc[m][n], 0, 0, 0);
    __syncthreads();
  }

  const int rb = (lane >> 4) * 4, cl = lane & 15;
  #pragma unroll
  for (int m = 0; m < 4; m++) {
    #pragma unroll
    for (int n = 0; n < 4; n++) {
      #pragma unroll
      for (int r = 0; r < 4; r++) {
        int c = wr * 64 + m * 16 + rb + r;
        int t = t0 + wc * 64 + n * 16 + cl;
        out[((size_t)b * 128 + c) * T_ + t] = acc[m][n][r] + bOut[c];
      }
    }
  }
}

extern "C" void kernel_launch(void* const* d_in, const int* in_sizes, int n_in,
                              void* d_out, int out_size, void* d_ws, size_t ws_size,
                              hipStream_t stream)
{
  const float* x    = (const float*)d_in[0];
  const float* cond = (const float*)d_in[1];
  const float* mask = (const float*)d_in[2];
  const float* wQ   = (const float*)d_in[3];
  const float* bQ   = (const float*)d_in[4];
  const float* wKV  = (const float*)d_in[5];
  const float* bKV  = (const float*)d_in[6];
  const float* wOut = (const float*)d_in[7];
  const float* bOut = (const float*)d_in[8];
  float* out = (float*)d_out;

  // Guard: never write past the harness workspace (a fault here kills the
  // container). If ws_size is insufficient, fail validation cleanly instead.
  if (ws_size < WS_NEEDED) return;

  char* ws = (char*)d_ws;
  u16* q     = (u16*)(ws + OFF_Q);
  u16* kT    = (u16*)(ws + OFF_KT);
  u16* attnT = (u16*)(ws + OFF_ATT);   // aliases kT
  u16* vT    = (u16*)(ws + OFF_VT);
  u16* kvT   = (u16*)(ws + OFF_KVT);
  u16* w2    = (u16*)(ws + OFF_W2);

  conv_q_kernel<<<dim3(256, 16), dim3(256), 0, stream>>>(cond, wQ, bQ, q);
  conv_kv_kernel<<<dim3(256, 16), dim3(512), 0, stream>>>(x, wKV, bKV, mask, kT, vT);
  prep_kernel<<<dim3(192), dim3(256), 0, stream>>>(wOut, w2);
  softmax_q_kernel<<<dim3(32768), dim3(256), 0, stream>>>(q);
  softmax_k_kernel<<<dim3(16384), dim3(256), 0, stream>>>(kT);
  // kv_mat^T[j][i] = sum_w vT[j][w] * kT[i][w]
  gemm_bt_kernel<0><<<dim3(8, 8, 16), dim3(256), 0, stream>>>(vT, kT, kvT, 1024, 1024, 2048);
  // attnT pad rows become safe to write only after gemm1 consumed kT
  zero_pad_kernel<<<dim3(16), dim3(256), 0, stream>>>(attnT);
  // attn[w][j] = sum_i q[w][i] * kvT[j][i]  -> written transposed+padded
  gemm_bt_kernel<1><<<dim3(16, 8, 16), dim3(256), 0, stream>>>(q, kvT, attnT, 2048, 1024, 1024);
  convout_kernel<<<dim3(1, 128, 16), dim3(256), 0, stream>>>(w2, attnT, bOut, out);
}

// Round 8
// 1089.747 us; speedup vs baseline: 1.1548x; 1.1548x over previous
//
#include <hip/hip_runtime.h>
#include <stdint.h>

// Problem constants (pad_x = 0 since T % PATCH == 0)
#define B_    16
#define C_    128
#define T_    16384
#define W_    2048      // wordnum
#define CP_   1024      // MIDC * PATCH

typedef unsigned short u16;
typedef __attribute__((ext_vector_type(4))) unsigned short u16x4;
typedef __attribute__((ext_vector_type(8))) unsigned short u16x8;
typedef __attribute__((ext_vector_type(8))) short bf16x8;   // MFMA A/B frag (8 bf16)
typedef __attribute__((ext_vector_type(4))) float f32x4;    // MFMA C/D frag

// Workspace layout (bytes) — attnT ALIASES kT (kT dead after GEMM1):
//  q     bf16 [16][2048][1024]     67108864   @ 0
//  kT    bf16 [16][1024][2048]     67108864   @ 67108864
//  attnT bf16 [16][16386][128]     67117056   @ 67108864   (alias; pads zeroed AFTER gemm1)
//  vT    bf16 [16][1024][2048]     67108864   @ 134234112
//  kvT   bf16 [16][1024][1024]     33554432   @ 201342976
//  w2    bf16 [3][128][128]           98304   @ 234897408
//  wQh/wQl  bf16 [128][160]  40960 each      @ 234995712 / 235036672
//  wKVh/wKVl bf16 [256][160] 81920 each      @ 235077632 / 235159552
#define OFF_Q     0ull
#define OFF_KT    67108864ull
#define OFF_ATT   67108864ull
#define OFF_VT    134234112ull
#define OFF_KVT   201342976ull
#define OFF_W2    234897408ull
#define OFF_WQH   234995712ull
#define OFF_WQL   235036672ull
#define OFF_WKH   235077632ull
#define OFF_WKL   235159552ull
#define WS_NEEDED 235241472ull

__device__ __forceinline__ u16 f2bf(float f) {
  union { float f; uint32_t u; } v; v.f = f;
  return (u16)((v.u + 0x7FFFu + ((v.u >> 16) & 1u)) >> 16);  // RNE
}
__device__ __forceinline__ float bf2f(u16 h) {
  union { uint32_t u; float f; } v; v.u = ((uint32_t)h) << 16;
  return v.f;
}
// hi = truncate-to-bf16 (exact prefix), lo = RNE(v - hi): v ≈ hi + lo to ~2^-17 rel
__device__ __forceinline__ void split2(float v, u16& h, u16& l) {
  union { float f; uint32_t u; } c; c.f = v;
  h = (u16)(c.u >> 16);
  union { uint32_t u; float f; } hf; hf.u = c.u & 0xFFFF0000u;
  l = f2bf(v - hf.f);
}
__device__ __forceinline__ void gload16(const void* g, void* l) {
  __builtin_amdgcn_global_load_lds(
      (const __attribute__((address_space(1))) uint32_t*)g,
      (__attribute__((address_space(3))) uint32_t*)l, 16, 0, 0);
}
__device__ __forceinline__ float wred_max(float v) {
  #pragma unroll
  for (int o = 32; o; o >>= 1) v = fmaxf(v, __shfl_xor(v, o));
  return v;
}
__device__ __forceinline__ float wred_sum(float v) {
  #pragma unroll
  for (int o = 32; o; o >>= 1) v += __shfl_xor(v, o);
  return v;
}

// ---------------------------------------------------------------------------
// conv_mfma v2: grouped conv (5 taps over words, pointwise over patch) as
// im2col + bf16 MFMA, 3-term split (wh*xh + wl*xh + wh*xl) => ~f32-exact.
// K ordered k = d*32 + ic. A (weights) pre-split in prep -> direct global
// u16x8 fragment loads (no A LDS). Input tile split hi/lo ONCE into LDS
// (Sh/Sl), B built from LDS scalar reads (conflict-free), single B buffer
// rebuilt for the lo pass. Per block: M=32 oc, N=128 t, K=160.
// MODE 0: q (4 chunks, g=chunk)   MODE 1: kv (8 chunks, g=chunk>>1;
//   chunks 0-3 -> kT (+mask), 4-7 -> vT; transposed layout [row][w])
// ---------------------------------------------------------------------------
#define TP 160
#define KP 168

template<int MODE>
__global__ __launch_bounds__(256) void conv_mfma_kernel(
    const float* __restrict__ in, const u16* __restrict__ wh,
    const u16* __restrict__ wl, const float* __restrict__ bias,
    const float* __restrict__ mask, u16* __restrict__ outA, u16* __restrict__ outV)
{
  __shared__ __align__(16) u16 lds[31744];   // Sh[32*160] | Sl[32*160] | Bt[128*168] = 63488 B
  u16* Sh = lds;
  u16* Sl = lds + 5120;
  u16* Bt = lds + 10240;

  const int tid = threadIdx.x, lane = tid & 63, wv = tid >> 6;
  const int t0 = blockIdx.x * 128;
  const int chunk = blockIdx.y;
  const int b = blockIdx.z;
  const int g = (MODE == 0) ? chunk : (chunk >> 1);
  const int oc0 = chunk * 32;
  const float* in_b = in + ((size_t)b * C_ + g * 32) * T_;

  const int wr = wv >> 1, wc = wv & 1;
  const int frow = lane & 15, fkq = lane >> 4;

  // ---- A fragments: direct global u16x8 loads (L2-hot after first blocks)
  bf16x8 ah[5], al[5];
  {
    const u16* hp = wh + (size_t)(oc0 + wr * 16 + frow) * 160 + fkq * 8;
    const u16* lp = wl + (size_t)(oc0 + wr * 16 + frow) * 160 + fkq * 8;
    #pragma unroll
    for (int s = 0; s < 5; s++) {
      ah[s] = *(const bf16x8*)(hp + s * 32);
      al[s] = *(const bf16x8*)(lp + s * 32);
    }
  }

  // ---- stage input tile [32 ic][160 t-local] f32 -> split -> Sh/Sl
  {
    #pragma unroll
    for (int it = 0; it < 5; it++) {
      int v = tid + it * 256;              // 1280 float4s
      int row = v / 40;
      int off = (v % 40) * 4;
      int gt = t0 - 16 + off;
      float4 val;
      if (gt >= 0 && gt + 3 < T_) {
        val = *(const float4*)(in_b + (size_t)row * T_ + gt);
      } else {
        float tmp[4];
        #pragma unroll
        for (int e = 0; e < 4; e++) {
          int tt = gt + e;
          tmp[e] = (tt >= 0 && tt < T_) ? in_b[(size_t)row * T_ + tt] : 0.f;
        }
        val = make_float4(tmp[0], tmp[1], tmp[2], tmp[3]);
      }
      float vf[4] = {val.x, val.y, val.z, val.w};
      u16x4 h4, l4;
      #pragma unroll
      for (int e = 0; e < 4; e++) {
        u16 hs, ls;
        split2(vf[e], hs, ls);
        h4[e] = hs;
        l4[e] = ls;
      }
      *(u16x4*)&Sh[row * TP + off] = h4;
      *(u16x4*)&Sl[row * TP + off] = l4;
    }
  }
  __syncthreads();

  // ---- build B (hi) : Bt[t][k=d*32+ic] = Sh[ic][t + d*8]
  {
    const int t = tid & 127, kg0 = tid >> 7;
    #pragma unroll
    for (int i = 0; i < 10; i++) {
      int kg = kg0 + i * 2;                // 0..19
      int d = kg >> 2, ic0 = (kg & 3) * 8;
      int sb = t + d * 8;
      u16x8 vv;
      #pragma unroll
      for (int e = 0; e < 8; e++) vv[e] = Sh[(ic0 + e) * TP + sb];
      *(u16x8*)&Bt[t * KP + kg * 8] = vv;
    }
  }
  __syncthreads();

  // ---- pass 1: (wh + wl) x Bh
  f32x4 acc[4];
  #pragma unroll
  for (int n = 0; n < 4; n++) acc[n] = (f32x4)0.f;
  #pragma unroll
  for (int s = 0; s < 5; s++) {
    #pragma unroll
    for (int n = 0; n < 4; n++) {
      bf16x8 bb = *(const bf16x8*)&Bt[(wc * 64 + n * 16 + frow) * KP + s * 32 + fkq * 8];
      acc[n] = __builtin_amdgcn_mfma_f32_16x16x32_bf16(ah[s], bb, acc[n], 0, 0, 0);
      acc[n] = __builtin_amdgcn_mfma_f32_16x16x32_bf16(al[s], bb, acc[n], 0, 0, 0);
    }
  }
  __syncthreads();

  // ---- rebuild B (lo)
  {
    const int t = tid & 127, kg0 = tid >> 7;
    #pragma unroll
    for (int i = 0; i < 10; i++) {
      int kg = kg0 + i * 2;
      int d = kg >> 2, ic0 = (kg & 3) * 8;
      int sb = t + d * 8;
      u16x8 vv;
      #pragma unroll
      for (int e = 0; e < 8; e++) vv[e] = Sl[(ic0 + e) * TP + sb];
      *(u16x8*)&Bt[t * KP + kg * 8] = vv;
    }
  }
  __syncthreads();

  // ---- pass 2: wh x Bl
  #pragma unroll
  for (int s = 0; s < 5; s++) {
    #pragma unroll
    for (int n = 0; n < 4; n++) {
      bf16x8 bb = *(const bf16x8*)&Bt[(wc * 64 + n * 16 + frow) * KP + s * 32 + fkq * 8];
      acc[n] = __builtin_amdgcn_mfma_f32_16x16x32_bf16(ah[s], bb, acc[n], 0, 0, 0);
    }
  }

  // ---- epilogue: bias (+mask for k chunks), LDS restage, coalesced write
  const int rb = (lane >> 4) * 4, cl = lane & 15;
  float bv[4];
  #pragma unroll
  for (int r = 0; r < 4; r++) bv[r] = bias[oc0 + wr * 16 + rb + r];
  if (MODE == 1 && chunk < 4) {
    #pragma unroll
    for (int n = 0; n < 4; n++) {
      int tcol = t0 + wc * 64 + n * 16 + cl;
      #pragma unroll
      for (int r = 0; r < 4; r++) {
        float mv = mask[((size_t)(b * 128 + oc0 + wr * 16 + rb + r)) * 16384 + tcol];
        acc[n][r] += bv[r] + mv;
      }
    }
  } else {
    #pragma unroll
    for (int n = 0; n < 4; n++)
      #pragma unroll
      for (int r = 0; r < 4; r++) acc[n][r] += bv[r];
  }
  __syncthreads();   // all Bt fragment reads done; reuse Bt region as stage

  if (MODE == 0) {
    u16* stg = Bt;   // stage[w16][264]: idx = wl*264 + row*8 + p
    #pragma unroll
    for (int n = 0; n < 4; n++) {
      int col = wc * 64 + n * 16 + cl;
      int wl_ = col >> 3, p = col & 7;
      #pragma unroll
      for (int r = 0; r < 4; r++)
        stg[wl_ * 264 + (wr * 16 + rb + r) * 8 + p] = f2bf(acc[n][r]);
    }
    __syncthreads();
    int wl_ = tid >> 4, seg = (tid & 15) * 16;
    u16x8 o0 = *(u16x8*)&stg[wl_ * 264 + seg];
    u16x8 o1 = *(u16x8*)&stg[wl_ * 264 + seg + 8];
    size_t ob = ((size_t)b * W_ + (t0 >> 3) + wl_) * CP_ + g * 256 + seg;
    *(u16x8*)&outA[ob] = o0;
    *(u16x8*)&outA[ob + 8] = o1;
  } else {
    u16* stg = Bt;   // stage[oc32][136]: idx = row*136 + p*16 + wl
    #pragma unroll
    for (int n = 0; n < 4; n++) {
      int col = wc * 64 + n * 16 + cl;
      int wl_ = col >> 3, p = col & 7;
      #pragma unroll
      for (int r = 0; r < 4; r++)
        stg[(wr * 16 + rb + r) * 136 + p * 16 + wl_] = f2bf(acc[n][r]);
    }
    __syncthreads();
    int ocl = tid >> 3, p = tid & 7;
    u16x8 o0 = *(u16x8*)&stg[ocl * 136 + p * 16];
    u16x8 o1 = *(u16x8*)&stg[ocl * 136 + p * 16 + 8];
    int w0 = t0 >> 3;
    u16* dst;
    size_t rowg;
    if (chunk < 4) { dst = outA; rowg = (size_t)b * CP_ + (oc0 + ocl) * 8 + p; }
    else           { dst = outV; rowg = (size_t)b * CP_ + (oc0 - 128 + ocl) * 8 + p; }
    *(u16x8*)&dst[rowg * W_ + w0] = o0;
    *(u16x8*)&dst[rowg * W_ + w0 + 8] = o1;
  }
}

// ---------------------------------------------------------------------------
// softmax over contiguous rows, in place.
// ---------------------------------------------------------------------------
__global__ __launch_bounds__(256) void softmax_q_kernel(u16* __restrict__ q)
{
  __shared__ float red[4];
  u16* p = q + (size_t)blockIdx.x * CP_ + threadIdx.x * 4;
  u16x4 raw = *(const u16x4*)p;
  float xv[4];
  #pragma unroll
  for (int e = 0; e < 4; e++) xv[e] = bf2f(raw[e]);
  float mx = fmaxf(fmaxf(xv[0], xv[1]), fmaxf(xv[2], xv[3]));
  mx = wred_max(mx);
  if ((threadIdx.x & 63) == 0) red[threadIdx.x >> 6] = mx;
  __syncthreads();
  mx = fmaxf(fmaxf(red[0], red[1]), fmaxf(red[2], red[3]));
  __syncthreads();
  float ev[4], s = 0.f;
  #pragma unroll
  for (int e = 0; e < 4; e++) { ev[e] = __expf(xv[e] - mx); s += ev[e]; }
  s = wred_sum(s);
  if ((threadIdx.x & 63) == 0) red[threadIdx.x >> 6] = s;
  __syncthreads();
  s = red[0] + red[1] + red[2] + red[3];
  float inv = 1.f / s;
  u16x4 o;
  #pragma unroll
  for (int e = 0; e < 4; e++) o[e] = f2bf(ev[e] * inv);
  *(u16x4*)p = o;
}

__global__ __launch_bounds__(256) void softmax_k_kernel(u16* __restrict__ kT)
{
  __shared__ float red[4];
  u16* p = kT + (size_t)blockIdx.x * W_ + threadIdx.x * 8;
  u16x8 raw = *(const u16x8*)p;
  float xv[8];
  #pragma unroll
  for (int e = 0; e < 8; e++) xv[e] = bf2f(raw[e]);
  float mx = -3.4e38f;
  #pragma unroll
  for (int e = 0; e < 8; e++) mx = fmaxf(mx, xv[e]);
  mx = wred_max(mx);
  if ((threadIdx.x & 63) == 0) red[threadIdx.x >> 6] = mx;
  __syncthreads();
  mx = fmaxf(fmaxf(red[0], red[1]), fmaxf(red[2], red[3]));
  __syncthreads();
  float ev[8], s = 0.f;
  #pragma unroll
  for (int e = 0; e < 8; e++) { ev[e] = __expf(xv[e] - mx); s += ev[e]; }
  s = wred_sum(s);
  if ((threadIdx.x & 63) == 0) red[threadIdx.x >> 6] = s;
  __syncthreads();
  s = red[0] + red[1] + red[2] + red[3];
  float inv = 1.f / s;
  u16x8 o;
  #pragma unroll
  for (int e = 0; e < 8; e++) o[e] = f2bf(ev[e] * inv);
  *(u16x8*)p = o;
}

// ---------------------------------------------------------------------------
// prep: pack w2[dt][c][m] = wOut[c][m][dt] (bf16) AND pre-split/reorder conv
// weights into wh/wl arrays with k = d*32 + ic.
// ---------------------------------------------------------------------------
__global__ __launch_bounds__(256) void prep_kernel(
    const float* __restrict__ wQ, const float* __restrict__ wKV,
    const float* __restrict__ wOut, u16* __restrict__ w2,
    u16* __restrict__ qh, u16* __restrict__ ql,
    u16* __restrict__ kvh, u16* __restrict__ kvl)
{
  int idx = blockIdx.x * 256 + threadIdx.x;
  if (idx < 3 * 128 * 128) {
    int dt = idx >> 14, c = (idx >> 7) & 127, m = idx & 127;
    w2[idx] = f2bf(wOut[((size_t)c * 128 + m) * 3 + dt]);
  }
  if (idx < 61440) {
    const float* src; u16 *dh, *dl; int oc;
    int k = idx % 160;
    if (idx < 20480) { oc = idx / 160; src = wQ;  dh = qh;  dl = ql; }
    else             { oc = (idx - 20480) / 160; src = wKV; dh = kvh; dl = kvl; }
    int d = k >> 5, ic = k & 31;
    float w = src[(size_t)oc * 160 + ic * 5 + d];
    u16 h, l;
    split2(w, h, l);
    dh[(size_t)oc * 160 + k] = h;
    dl[(size_t)oc * 160 + k] = l;
  }
}

// zero the attnT pad rows (row 0 and row T_+1 per batch). Launched AFTER gemm1.
__global__ __launch_bounds__(256) void zero_pad_kernel(u16* __restrict__ attnT)
{
  int idx = blockIdx.x * 256 + threadIdx.x;   // 16*2*128 = 4096
  int b = idx >> 8, r = (idx >> 7) & 1, m = idx & 127;
  attnT[((size_t)b * (T_ + 2) + (r ? (T_ + 1) : 0)) * 128 + m] = 0;
}

// ---------------------------------------------------------------------------
// gemm_bt: C[M x N] = A[M x K] * Bt[N x K]^T  (bf16 in, f32 acc), batched.
// 128x128 tile, BK=32, 4 waves (2x2), mfma_f32_16x16x32_bf16.
// XOR k-slot swizzle on BOTH global source (staging) and LDS read (rule #21).
// MODE 0: out[b][row][col]  (kvT)
// MODE 1: out = attnT[b][1 + row*8 + (col&7)][col>>3]  (padded transposed attn)
// ---------------------------------------------------------------------------
template<int MODE>
__global__ __launch_bounds__(256) void gemm_bt_kernel(
    const u16* __restrict__ A, const u16* __restrict__ Bt, u16* __restrict__ out,
    int M, int N, int K)
{
  __shared__ __align__(16) u16 ldsA[4096];
  __shared__ __align__(16) u16 ldsB[4096];
  const int b = blockIdx.z;
  const int i0 = blockIdx.x * 128, j0 = blockIdx.y * 128;
  const int tid = threadIdx.x, lane = tid & 63, wv = tid >> 6;
  const int wr = wv >> 1, wc = wv & 1;
  const u16* Ab = A + (size_t)b * M * K + (size_t)i0 * K;
  const u16* Bb = Bt + (size_t)b * N * K + (size_t)j0 * K;

  const int srow0 = wv * 32 + (lane >> 2);
  const int sslot = lane & 3;
  const int frow = lane & 15, fkq = lane >> 4;

  f32x4 acc[4][4];
  #pragma unroll
  for (int m = 0; m < 4; m++)
    #pragma unroll
    for (int n = 0; n < 4; n++) acc[m][n] = (f32x4)0.f;

  for (int kt = 0; kt < K; kt += 32) {
    #pragma unroll
    for (int q = 0; q < 2; q++) {
      int row = srow0 + q * 16;
      int gslot = sslot ^ ((row >> 1) & 3);
      gload16(Ab + (size_t)row * K + kt + gslot * 8, &ldsA[row * 32 + sslot * 8]);
      gload16(Bb + (size_t)row * K + kt + gslot * 8, &ldsB[row * 32 + sslot * 8]);
    }
    __syncthreads();
    bf16x8 af[4], bf[4];
    #pragma unroll
    for (int m = 0; m < 4; m++) {
      int row = wr * 64 + m * 16 + frow;
      af[m] = *(const bf16x8*)&ldsA[row * 32 + (fkq ^ ((row >> 1) & 3)) * 8];
    }
    #pragma unroll
    for (int n = 0; n < 4; n++) {
      int row = wc * 64 + n * 16 + frow;
      bf[n] = *(const bf16x8*)&ldsB[row * 32 + (fkq ^ ((row >> 1) & 3)) * 8];
    }
    #pragma unroll
    for (int m = 0; m < 4; m++)
      #pragma unroll
      for (int n = 0; n < 4; n++)
        acc[m][n] = __builtin_amdgcn_mfma_f32_16x16x32_bf16(af[m], bf[n], acc[m][n], 0, 0, 0);
    __syncthreads();
  }

  const int rb = (lane >> 4) * 4, cl = lane & 15;
  #pragma unroll
  for (int m = 0; m < 4; m++) {
    #pragma unroll
    for (int n = 0; n < 4; n++) {
      #pragma unroll
      for (int r = 0; r < 4; r++) {
        int gr = i0 + wr * 64 + m * 16 + rb + r;
        int gc = j0 + wc * 64 + n * 16 + cl;
        u16 v = f2bf(acc[m][n][r]);
        if (MODE == 0) {
          out[((size_t)b * M + gr) * N + gc] = v;
        } else {
          out[((size_t)b * (T_ + 2) + 1 + (size_t)gr * 8 + (gc & 7)) * 128 + (gc >> 3)] = v;
        }
      }
    }
  }
}

// ---------------------------------------------------------------------------
// convout: final conv1d as 3 shifted GEMMs accumulated in one K-loop.
// C[c][t] = bOut[c] + sum_dt sum_m w2[dt][c][m] * attnT[b][t+dt][m]
// ---------------------------------------------------------------------------
__global__ __launch_bounds__(256) void convout_kernel(
    const u16* __restrict__ w2, const u16* __restrict__ attnT,
    const float* __restrict__ bOut, float* __restrict__ out)
{
  __shared__ __align__(16) u16 ldsA[4096];
  __shared__ __align__(16) u16 ldsB[4096];
  const int b = blockIdx.z;
  const int t0 = blockIdx.y * 128;
  const int tid = threadIdx.x, lane = tid & 63, wv = tid >> 6;
  const int wr = wv >> 1, wc = wv & 1;
  const u16* Bb = attnT + (size_t)b * (T_ + 2) * 128;

  const int srow0 = wv * 32 + (lane >> 2);
  const int sslot = lane & 3;
  const int frow = lane & 15, fkq = lane >> 4;

  f32x4 acc[4][4];
  #pragma unroll
  for (int m = 0; m < 4; m++)
    #pragma unroll
    for (int n = 0; n < 4; n++) acc[m][n] = (f32x4)0.f;

  for (int s = 0; s < 12; s++) {
    int dt = s >> 2, kk = (s & 3) * 32;
    #pragma unroll
    for (int q = 0; q < 2; q++) {
      int row = srow0 + q * 16;
      int gslot = sslot ^ ((row >> 1) & 3);
      gload16(w2 + (size_t)dt * 16384 + (size_t)row * 128 + kk + gslot * 8,
              &ldsA[row * 32 + sslot * 8]);
      gload16(Bb + (size_t)(t0 + row + dt) * 128 + kk + gslot * 8,
              &ldsB[row * 32 + sslot * 8]);
    }
    __syncthreads();
    bf16x8 af[4], bf[4];
    #pragma unroll
    for (int m = 0; m < 4; m++) {
      int row = wr * 64 + m * 16 + frow;
      af[m] = *(const bf16x8*)&ldsA[row * 32 + (fkq ^ ((row >> 1) & 3)) * 8];
    }
    #pragma unroll
    for (int n = 0; n < 4; n++) {
      int row = wc * 64 + n * 16 + frow;
      bf[n] = *(const bf16x8*)&ldsB[row * 32 + (fkq ^ ((row >> 1) & 3)) * 8];
    }
    #pragma unroll
    for (int m = 0; m < 4; m++)
      #pragma unroll
      for (int n = 0; n < 4; n++)
        acc[m][n] = __builtin_amdgcn_mfma_f32_16x16x32_bf16(af[m], bf[n], acc[m][n], 0, 0, 0);
    __syncthreads();
  }

  const int rb = (lane >> 4) * 4, cl = lane & 15;
  #pragma unroll
  for (int m = 0; m < 4; m++) {
    #pragma unroll
    for (int n = 0; n < 4; n++) {
      #pragma unroll
      for (int r = 0; r < 4; r++) {
        int c = wr * 64 + m * 16 + rb + r;
        int t = t0 + wc * 64 + n * 16 + cl;
        out[((size_t)b * 128 + c) * T_ + t] = acc[m][n][r] + bOut[c];
      }
    }
  }
}

extern "C" void kernel_launch(void* const* d_in, const int* in_sizes, int n_in,
                              void* d_out, int out_size, void* d_ws, size_t ws_size,
                              hipStream_t stream)
{
  const float* x    = (const float*)d_in[0];
  const float* cond = (const float*)d_in[1];
  const float* mask = (const float*)d_in[2];
  const float* wQ   = (const float*)d_in[3];
  const float* bQ   = (const float*)d_in[4];
  const float* wKV  = (const float*)d_in[5];
  const float* bKV  = (const float*)d_in[6];
  const float* wOut = (const float*)d_in[7];
  const float* bOut = (const float*)d_in[8];
  float* out = (float*)d_out;

  if (ws_size < WS_NEEDED) return;   // clean validation failure, not a fault

  char* ws = (char*)d_ws;
  u16* q     = (u16*)(ws + OFF_Q);
  u16* kT    = (u16*)(ws + OFF_KT);
  u16* attnT = (u16*)(ws + OFF_ATT);   // aliases kT
  u16* vT    = (u16*)(ws + OFF_VT);
  u16* kvT   = (u16*)(ws + OFF_KVT);
  u16* w2    = (u16*)(ws + OFF_W2);
  u16* wQh   = (u16*)(ws + OFF_WQH);
  u16* wQl   = (u16*)(ws + OFF_WQL);
  u16* wKVh  = (u16*)(ws + OFF_WKH);
  u16* wKVl  = (u16*)(ws + OFF_WKL);

  // prep FIRST: convs consume the pre-split weights
  prep_kernel<<<dim3(240), dim3(256), 0, stream>>>(wQ, wKV, wOut, w2, wQh, wQl, wKVh, wKVl);
  conv_mfma_kernel<0><<<dim3(128, 4, 16), dim3(256), 0, stream>>>(cond, wQh, wQl, bQ, nullptr, q, nullptr);
  conv_mfma_kernel<1><<<dim3(128, 8, 16), dim3(256), 0, stream>>>(x, wKVh, wKVl, bKV, mask, kT, vT);
  softmax_q_kernel<<<dim3(32768), dim3(256), 0, stream>>>(q);
  softmax_k_kernel<<<dim3(16384), dim3(256), 0, stream>>>(kT);
  // kv_mat^T[j][i] = sum_w vT[j][w] * kT[i][w]
  gemm_bt_kernel<0><<<dim3(8, 8, 16), dim3(256), 0, stream>>>(vT, kT, kvT, 1024, 1024, 2048);
  // attnT pad rows become safe to write only after gemm1 consumed kT
  zero_pad_kernel<<<dim3(16), dim3(256), 0, stream>>>(attnT);
  // attn[w][j] = sum_i q[w][i] * kvT[j][i]  -> written transposed+padded
  gemm_bt_kernel<1><<<dim3(16, 8, 16), dim3(256), 0, stream>>>(q, kvT, attnT, 2048, 1024, 1024);
  convout_kernel<<<dim3(1, 128, 16), dim3(256), 0, stream>>>(w2, attnT, bOut, out);
}